// Round 3
// baseline (866.900 us; speedup 1.0000x reference)
//
#include <hip/hip_runtime.h>
#include <hip/hip_bf16.h>

typedef __bf16 bf16x8 __attribute__((ext_vector_type(8)));
typedef float  f32x4  __attribute__((ext_vector_type(4)));

#define BN_EPS 1e-5f
#define NROWS 131072
#define TPB 512               // 8 waves; wave w owns output cols [w*32, w*32+32)
#define TILES_PER_BLK 8       // 16-row tiles per block
#define NBLOCKS (NROWS / (16 * TILES_PER_BLK))   // 1024

// ws layout (bytes):
//   [0, 262144)        W0 packed bf16, fragment order [s][t][lane][8]
//   [262144, 264192)   a_fused f32[512]
//   [264192, 266240)   c_fused f32[512]
//   [266240, 267264)   A_fc f32[256]
//   [267264, 268288)   C_fc f32[256] (b0 folded in)

__global__ __launch_bounds__(256) void setup_kernel(
    const float* __restrict__ W0,
    const float* __restrict__ imu_gamma, const float* __restrict__ imu_beta,
    const float* __restrict__ imu_mean,  const float* __restrict__ imu_var,
    const float* __restrict__ frame_gamma, const float* __restrict__ frame_beta,
    const float* __restrict__ frame_mean,  const float* __restrict__ frame_var,
    const float* __restrict__ b0,
    const float* __restrict__ fc_gamma, const float* __restrict__ fc_beta,
    const float* __restrict__ fc_mean,  const float* __restrict__ fc_var,
    void* __restrict__ ws)
{
    __bf16* w0p    = (__bf16*)ws;
    float* a_fused = (float*)((char*)ws + 262144);
    float* c_fused = a_fused + 512;
    float* A_fc    = c_fused + 512;
    float* C_fc    = A_fc + 256;

    const int b = blockIdx.x;
    if (b < 512) {
        // pack W0[n][k] into B-fragment order:
        // flat = ((s*16 + t)*64 + lane)*8 + j ; n = t*16+(lane&15); k = s*32+(lane>>4)*8+j
        const int flat = b * 256 + threadIdx.x;
        const int j    = flat & 7;
        const int lane = (flat >> 3) & 63;
        const int t    = (flat >> 9) & 15;
        const int s    = flat >> 13;
        const int n    = t * 16 + (lane & 15);
        const int k    = s * 32 + ((lane >> 4) << 3) + j;
        w0p[flat] = (__bf16)W0[n * 512 + k];
    } else {
        const int t = threadIdx.x;
        const float af = frame_gamma[t] / sqrtf(frame_var[t] + BN_EPS);
        a_fused[t]       = af;
        c_fused[t]       = frame_beta[t] - frame_mean[t] * af;
        const float ai = imu_gamma[t] / sqrtf(imu_var[t] + BN_EPS);
        a_fused[256 + t] = ai;
        c_fused[256 + t] = imu_beta[t] - imu_mean[t] * ai;
        const float A = fc_gamma[t] / sqrtf(fc_var[t] + BN_EPS);
        A_fc[t] = A;
        C_fc[t] = fc_beta[t] - fc_mean[t] * A + A * b0[t];
    }
}

__global__ __launch_bounds__(TPB, 2) void fusion_main(
    const float* __restrict__ frame, const float* __restrict__ imu,
    const float* __restrict__ W1,    const float* __restrict__ b1,
    const void* __restrict__ ws_c,   float* __restrict__ out)
{
    const __bf16* w0p     = (const __bf16*)ws_c;
    const float*  a_fused = (const float*)((const char*)ws_c + 262144);
    const float*  c_fused = a_fused + 512;
    const float*  A_fc    = c_fused + 512;
    const float*  C_fc    = A_fc + 256;

    // per-tile fc1 partials: [tile][row*16 + wave*2 + m]; reduced once at block end
    __shared__ float cbuf[TILES_PER_BLK][256];

    const int tid  = threadIdx.x;
    const int wave = tid >> 6;
    const int lane = tid & 63;
    const int nc   = lane & 15;   // A-frag row == C-frag col-in-tile
    const int kg   = lane >> 4;   // k-group (8 contiguous k)

    // ---- W0 register-resident: wave owns col-tiles t0 = 2*wave, t1 = 2*wave+1 ----
    const bf16x8* wsrc = (const bf16x8*)w0p;   // element idx = (s*16+t)*64 + lane
    bf16x8 B0[16], B1[16];
    #pragma unroll
    for (int s = 0; s < 16; ++s) {
        B0[s] = wsrc[(s * 16 + 2 * wave + 0) * 64 + lane];
        B1[s] = wsrc[(s * 16 + 2 * wave + 1) * 64 + lane];
    }
    // fc-BN + W1 scalars for this lane's two output cols
    const int n0 = (2 * wave) * 16 + nc;
    const int n1 = n0 + 16;
    const float Afc0 = A_fc[n0], Cfc0 = C_fc[n0];
    const float Afc1 = A_fc[n1], Cfc1 = C_fc[n1];
    const float w00 = W1[n0], w01 = W1[n1];
    const float w10 = W1[256 + n0], w11 = W1[256 + n1];
    const float b1_0 = b1[0], b1_1 = b1[1];

    #pragma unroll 1
    for (int it = 0; it < TILES_PER_BLK; ++it) {
        const size_t rowBase = ((size_t)blockIdx.x * TILES_PER_BLK + it) * 16;
        f32x4 acc0 = {0.f, 0.f, 0.f, 0.f};
        f32x4 acc1 = {0.f, 0.f, 0.f, 0.f};

        #pragma unroll
        for (int s = 0; s < 16; ++s) {
            const float* src = (s < 8) ? frame : imu;   // fused = [frame | imu]
            const float* xp  = src + (rowBase + nc) * 256 + (s & 7) * 32 + kg * 8;
            const float4 x0 = *(const float4*)xp;
            const float4 x1 = *(const float4*)(xp + 4);
            const int kf = s * 32 + kg * 8;
            const float4 a0 = *(const float4*)(a_fused + kf);
            const float4 a1 = *(const float4*)(a_fused + kf + 4);
            const float4 c0 = *(const float4*)(c_fused + kf);
            const float4 c1 = *(const float4*)(c_fused + kf + 4);
            bf16x8 af;
            af[0] = (__bf16)fmaxf(fmaf(a0.x, x0.x, c0.x), 0.f);
            af[1] = (__bf16)fmaxf(fmaf(a0.y, x0.y, c0.y), 0.f);
            af[2] = (__bf16)fmaxf(fmaf(a0.z, x0.z, c0.z), 0.f);
            af[3] = (__bf16)fmaxf(fmaf(a0.w, x0.w, c0.w), 0.f);
            af[4] = (__bf16)fmaxf(fmaf(a1.x, x1.x, c1.x), 0.f);
            af[5] = (__bf16)fmaxf(fmaf(a1.y, x1.y, c1.y), 0.f);
            af[6] = (__bf16)fmaxf(fmaf(a1.z, x1.z, c1.z), 0.f);
            af[7] = (__bf16)fmaxf(fmaf(a1.w, x1.w, c1.w), 0.f);
            acc0 = __builtin_amdgcn_mfma_f32_16x16x32_bf16(af, B0[s], acc0, 0, 0, 0);
            acc1 = __builtin_amdgcn_mfma_f32_16x16x32_bf16(af, B1[s], acc1, 0, 0, 0);
        }

        // fc BN + ReLU + fc1 partial over this wave's 32 cols
        // C/D layout: col-in-tile = nc, row = kg*4 + q
        float p0[4], p1[4];
        #pragma unroll
        for (int q = 0; q < 4; ++q) {
            const float h0 = fmaxf(fmaf(Afc0, acc0[q], Cfc0), 0.f);
            const float h1 = fmaxf(fmaf(Afc1, acc1[q], Cfc1), 0.f);
            p0[q] = fmaf(h1, w01, h0 * w00);
            p1[q] = fmaf(h1, w11, h0 * w10);
        }
        #pragma unroll
        for (int off = 1; off < 16; off <<= 1) {
            #pragma unroll
            for (int q = 0; q < 4; ++q) {
                p0[q] += __shfl_xor(p0[q], off, 64);
                p1[q] += __shfl_xor(p1[q], off, 64);
            }
        }
        if (nc < 8) {   // lane nc = q*2+m parks partial for row kg*4+q, output m
            const int q = nc >> 1, m = nc & 1;
            cbuf[it][(kg * 4 + q) * 16 + wave * 2 + m] = m ? p1[q] : p0[q];
        }
    }

    __syncthreads();   // single barrier per block

    // final cross-wave reduce: 256 threads cover [tile][row][m]
    if (tid < 256) {
        const int t2  = tid >> 5;         // tile 0..7
        const int row = (tid >> 1) & 15;  // row in tile
        const int m   = tid & 1;
        float sum = 0.f;
        #pragma unroll
        for (int w = 0; w < 8; ++w) sum += cbuf[t2][row * 16 + w * 2 + m];
        float v = fmaxf(sum + (m ? b1_1 : b1_0), 0.f);
        v = fminf(v, m ? 384.f : 512.f);
        const size_t grow = ((size_t)blockIdx.x * TILES_PER_BLK + t2) * 16 + row;
        out[grow * 2 + m] = v;
    }
}

extern "C" void kernel_launch(void* const* d_in, const int* in_sizes, int n_in,
                              void* d_out, int out_size, void* d_ws, size_t ws_size,
                              hipStream_t stream) {
    const float* frame_feat  = (const float*)d_in[0];
    const float* imu_feat    = (const float*)d_in[1];
    const float* imu_gamma   = (const float*)d_in[2];
    const float* imu_beta    = (const float*)d_in[3];
    const float* imu_mean    = (const float*)d_in[4];
    const float* imu_var     = (const float*)d_in[5];
    const float* frame_gamma = (const float*)d_in[6];
    const float* frame_beta  = (const float*)d_in[7];
    const float* frame_mean  = (const float*)d_in[8];
    const float* frame_var   = (const float*)d_in[9];
    const float* W0          = (const float*)d_in[10];
    const float* b0          = (const float*)d_in[11];
    const float* fc_gamma    = (const float*)d_in[12];
    const float* fc_beta     = (const float*)d_in[13];
    const float* fc_mean     = (const float*)d_in[14];
    const float* fc_var      = (const float*)d_in[15];
    const float* W1          = (const float*)d_in[16];
    const float* b1          = (const float*)d_in[17];

    setup_kernel<<<513, 256, 0, stream>>>(
        W0, imu_gamma, imu_beta, imu_mean, imu_var,
        frame_gamma, frame_beta, frame_mean, frame_var,
        b0, fc_gamma, fc_beta, fc_mean, fc_var, d_ws);

    fusion_main<<<NBLOCKS, TPB, 0, stream>>>(
        frame_feat, imu_feat, W1, b1, d_ws, (float*)d_out);
}

// Round 4
// 92.367 us; speedup vs baseline: 9.3854x; 9.3854x over previous
//
#include <hip/hip_runtime.h>
#include <hip/hip_bf16.h>

typedef __bf16 bf16x8 __attribute__((ext_vector_type(8)));
typedef float  f32x4  __attribute__((ext_vector_type(4)));

#define BN_EPS 1e-5f
#define NROWS 131072
#define TPB 512               // 8 waves; each wave owns 32 rows x all 256 cols
#define BM 256                // rows per block
#define NBLOCKS (NROWS / BM)  // 512

__device__ __forceinline__ void gll16(const void* g, void* l) {
    __builtin_amdgcn_global_load_lds(
        (const __attribute__((address_space(1))) void*)g,
        (__attribute__((address_space(3))) void*)l, 16, 0, 0);
}

// ws layout (bytes):
//   [0, 262144)        W0 packed bf16, fragment order [s][t][lane][8]
//   [262144, 264192)   a_fused f32[512]
//   [264192, 266240)   c_fused f32[512]
//   [266240, 267264)   A_fc f32[256]
//   [267264, 268288)   C_fc f32[256] (b0 folded in)

__global__ __launch_bounds__(256) void setup_kernel(
    const float* __restrict__ W0,
    const float* __restrict__ imu_gamma, const float* __restrict__ imu_beta,
    const float* __restrict__ imu_mean,  const float* __restrict__ imu_var,
    const float* __restrict__ frame_gamma, const float* __restrict__ frame_beta,
    const float* __restrict__ frame_mean,  const float* __restrict__ frame_var,
    const float* __restrict__ b0,
    const float* __restrict__ fc_gamma, const float* __restrict__ fc_beta,
    const float* __restrict__ fc_mean,  const float* __restrict__ fc_var,
    void* __restrict__ ws)
{
    __bf16* w0p    = (__bf16*)ws;
    float* a_fused = (float*)((char*)ws + 262144);
    float* c_fused = a_fused + 512;
    float* A_fc    = c_fused + 512;
    float* C_fc    = A_fc + 256;

    const int b = blockIdx.x;
    if (b < 512) {
        // flat = ((s*16 + t)*64 + lane)*8 + j ; n = t*16+(lane&15); k = s*32+(lane>>4)*8+j
        const int flat = b * 256 + threadIdx.x;
        const int j    = flat & 7;
        const int lane = (flat >> 3) & 63;
        const int t    = (flat >> 9) & 15;
        const int s    = flat >> 13;
        const int n    = t * 16 + (lane & 15);
        const int k    = s * 32 + ((lane >> 4) << 3) + j;
        w0p[flat] = (__bf16)W0[n * 512 + k];
    } else {
        const int t = threadIdx.x;
        const float af = frame_gamma[t] / sqrtf(frame_var[t] + BN_EPS);
        a_fused[t]       = af;
        c_fused[t]       = frame_beta[t] - frame_mean[t] * af;
        const float ai = imu_gamma[t] / sqrtf(imu_var[t] + BN_EPS);
        a_fused[256 + t] = ai;
        c_fused[256 + t] = imu_beta[t] - imu_mean[t] * ai;
        const float A = fc_gamma[t] / sqrtf(fc_var[t] + BN_EPS);
        A_fc[t] = A;
        C_fc[t] = fc_beta[t] - fc_mean[t] * A + A * b0[t];
    }
}

__global__ __launch_bounds__(TPB, 2) void fusion_main(
    const float* __restrict__ frame, const float* __restrict__ imu,
    const float* __restrict__ W1,    const float* __restrict__ b1,
    const void* __restrict__ ws_c,   float* __restrict__ out)
{
    const __bf16* w0p     = (const __bf16*)ws_c;
    const float*  a_fused = (const float*)((const char*)ws_c + 262144);
    const float*  c_fused = a_fused + 512;
    const float*  A_fc    = c_fused + 512;
    const float*  C_fc    = A_fc + 256;

    // one K-half of the full-N W0 panel: 256 cols x 256 k x bf16 = 128 KB
    __shared__ __align__(16) __bf16 bsh[65536];

    const int tid  = threadIdx.x;
    const int wave = tid >> 6;
    const int lane = tid & 63;
    const int nc   = lane & 15;
    const int kg   = lane >> 4;
    const size_t rowW = (size_t)blockIdx.x * BM + wave * 32;  // wave's 32 rows

    f32x4 acc[2][16];   // [m-frag][t-tile] -> 128 AGPRs
    #pragma unroll
    for (int m = 0; m < 2; ++m)
        #pragma unroll
        for (int t = 0; t < 16; ++t) acc[m][t] = (f32x4){0.f, 0.f, 0.f, 0.f};

    auto stage = [&](int h) {   // copy K-half h of packed W0 -> LDS (linear)
        const char* src = (const char*)w0p + (size_t)h * 131072 + tid * 16;
        #pragma unroll
        for (int i = 0; i < 16; ++i)
            gll16(src + i * 8192, (char*)bsh + i * 8192 + wave * 1024);
    };

    float4 pxA[2][2], pxB[2][2];   // feature ping-pong, [m-frag][pair]

    auto issue = [&](int s, float4 (*px)[2]) {
        const float* srcp = (s < 8) ? frame : imu;   // K-half == modality
        #pragma unroll
        for (int m = 0; m < 2; ++m) {
            const float* xp = srcp + (rowW + m * 16 + nc) * 256 + (s & 7) * 32 + kg * 8;
            px[m][0] = *(const float4*)xp;
            px[m][1] = *(const float4*)(xp + 4);
        }
    };

    auto step = [&](int s, float4 (*px)[2]) {
        const int kf = s * 32 + kg * 8;
        const float4 a0 = *(const float4*)(a_fused + kf);
        const float4 a1 = *(const float4*)(a_fused + kf + 4);
        const float4 c0 = *(const float4*)(c_fused + kf);
        const float4 c1 = *(const float4*)(c_fused + kf + 4);
        bf16x8 af[2];
        #pragma unroll
        for (int m = 0; m < 2; ++m) {
            const float4 x0 = px[m][0], x1 = px[m][1];
            af[m][0] = (__bf16)fmaxf(fmaf(a0.x, x0.x, c0.x), 0.f);
            af[m][1] = (__bf16)fmaxf(fmaf(a0.y, x0.y, c0.y), 0.f);
            af[m][2] = (__bf16)fmaxf(fmaf(a0.z, x0.z, c0.z), 0.f);
            af[m][3] = (__bf16)fmaxf(fmaf(a0.w, x0.w, c0.w), 0.f);
            af[m][4] = (__bf16)fmaxf(fmaf(a1.x, x1.x, c1.x), 0.f);
            af[m][5] = (__bf16)fmaxf(fmaf(a1.y, x1.y, c1.y), 0.f);
            af[m][6] = (__bf16)fmaxf(fmaf(a1.z, x1.z, c1.z), 0.f);
            af[m][7] = (__bf16)fmaxf(fmaf(a1.w, x1.w, c1.w), 0.f);
        }
        #pragma unroll
        for (int t = 0; t < 16; ++t) {
            const bf16x8 bfr = *(const bf16x8*)(bsh + (((s & 7) * 16 + t) * 64 + lane) * 8);
            acc[0][t] = __builtin_amdgcn_mfma_f32_16x16x32_bf16(af[0], bfr, acc[0][t], 0, 0, 0);
            acc[1][t] = __builtin_amdgcn_mfma_f32_16x16x32_bf16(af[1], bfr, acc[1][t], 0, 0, 0);
        }
    };

    // ---- half 0 (frame) ----
    stage(0);
    __syncthreads();
    issue(0, pxA);
    #pragma unroll
    for (int s = 0; s < 8; ++s) {
        if (s < 7) issue(s + 1, (s & 1) ? pxA : pxB);
        step(s, (s & 1) ? pxB : pxA);
    }
    __syncthreads();        // all waves done reading half 0
    // ---- half 1 (imu) ----
    stage(1);
    issue(8, pxA);
    __syncthreads();        // staging (and prefetch) complete
    #pragma unroll
    for (int s = 8; s < 16; ++s) {
        if (s < 15) issue(s + 1, (s & 1) ? pxA : pxB);
        step(s, (s & 1) ? pxB : pxA);
    }

    // ---- epilogue: fc BN+ReLU + fc1 + ReLU + clamp (wave-local over full N) ----
    // C/D layout: col = t*16 + nc, row = m*16 + kg*4 + q
    const float b1_0 = b1[0], b1_1 = b1[1];
    float p[2][2][4];
    #pragma unroll
    for (int m = 0; m < 2; ++m)
        #pragma unroll
        for (int o = 0; o < 2; ++o)
            #pragma unroll
            for (int q = 0; q < 4; ++q) p[m][o][q] = 0.f;

    #pragma unroll
    for (int t = 0; t < 16; ++t) {
        const int n = t * 16 + nc;
        const float A = A_fc[n], C = C_fc[n];
        const float w0n = W1[n], w1n = W1[256 + n];
        #pragma unroll
        for (int m = 0; m < 2; ++m) {
            #pragma unroll
            for (int q = 0; q < 4; ++q) {
                const float h = fmaxf(fmaf(A, acc[m][t][q], C), 0.f);
                p[m][0][q] = fmaf(h, w0n, p[m][0][q]);
                p[m][1][q] = fmaf(h, w1n, p[m][1][q]);
            }
        }
    }
    #pragma unroll
    for (int off = 1; off < 16; off <<= 1) {
        #pragma unroll
        for (int m = 0; m < 2; ++m)
            #pragma unroll
            for (int o = 0; o < 2; ++o)
                #pragma unroll
                for (int q = 0; q < 4; ++q)
                    p[m][o][q] += __shfl_xor(p[m][o][q], off, 64);
    }
    if (nc < 8) {   // lane nc = q*2 + mo writes rows kg*4+q, output mo
        const int q = nc >> 1, mo = nc & 1;
        #pragma unroll
        for (int m = 0; m < 2; ++m) {
            const float v0 = (q == 0) ? p[m][0][0] : (q == 1) ? p[m][0][1]
                           : (q == 2) ? p[m][0][2] : p[m][0][3];
            const float v1 = (q == 0) ? p[m][1][0] : (q == 1) ? p[m][1][1]
                           : (q == 2) ? p[m][1][2] : p[m][1][3];
            float v = mo ? v1 : v0;
            v = fmaxf(v + (mo ? b1_1 : b1_0), 0.f);
            v = fminf(v, mo ? 384.f : 512.f);
            const size_t row = rowW + m * 16 + kg * 4 + q;
            out[row * 2 + mo] = v;
        }
    }
}

extern "C" void kernel_launch(void* const* d_in, const int* in_sizes, int n_in,
                              void* d_out, int out_size, void* d_ws, size_t ws_size,
                              hipStream_t stream) {
    const float* frame_feat  = (const float*)d_in[0];
    const float* imu_feat    = (const float*)d_in[1];
    const float* imu_gamma   = (const float*)d_in[2];
    const float* imu_beta    = (const float*)d_in[3];
    const float* imu_mean    = (const float*)d_in[4];
    const float* imu_var     = (const float*)d_in[5];
    const float* frame_gamma = (const float*)d_in[6];
    const float* frame_beta  = (const float*)d_in[7];
    const float* frame_mean  = (const float*)d_in[8];
    const float* frame_var   = (const float*)d_in[9];
    const float* W0          = (const float*)d_in[10];
    const float* b0          = (const float*)d_in[11];
    const float* fc_gamma    = (const float*)d_in[12];
    const float* fc_beta     = (const float*)d_in[13];
    const float* fc_mean     = (const float*)d_in[14];
    const float* fc_var      = (const float*)d_in[15];
    const float* W1          = (const float*)d_in[16];
    const float* b1          = (const float*)d_in[17];

    setup_kernel<<<513, 256, 0, stream>>>(
        W0, imu_gamma, imu_beta, imu_mean, imu_var,
        frame_gamma, frame_beta, frame_mean, frame_var,
        b0, fc_gamma, fc_beta, fc_mean, fc_var, d_ws);

    fusion_main<<<NBLOCKS, TPB, 0, stream>>>(
        frame_feat, imu_feat, W1, b1, d_ws, (float*)d_out);
}

// Round 5
// 76.281 us; speedup vs baseline: 11.3646x; 1.2109x over previous
//
#include <hip/hip_runtime.h>
#include <hip/hip_bf16.h>

typedef __bf16 bf16x8 __attribute__((ext_vector_type(8)));
typedef float  f32x4  __attribute__((ext_vector_type(4)));

#define BN_EPS 1e-5f
#define NROWS 131072
#define TPB 512               // 8 waves; wave owns 16 rows x all 256 cols
#define BM 128                // rows per block
#define NBLOCKS (NROWS / BM)  // 1024

#define WAITVM(N) asm volatile("s_waitcnt vmcnt(" #N ")" ::: "memory")

__device__ __forceinline__ void gll16(const void* g, void* l) {
    __builtin_amdgcn_global_load_lds(
        (const __attribute__((address_space(1))) void*)g,
        (__attribute__((address_space(3))) void*)l, 16, 0, 0);
}

// ws layout (bytes):
//   [0, 262144)        W0 packed bf16, fragment order [s][t][lane][8]
//   [262144, 264192)   a_fused f32[512]
//   [264192, 266240)   c_fused f32[512]
//   [266240, 267264)   A_fc f32[256]
//   [267264, 268288)   C_fc f32[256] (b0 folded in)

__global__ __launch_bounds__(256) void setup_kernel(
    const float* __restrict__ W0,
    const float* __restrict__ imu_gamma, const float* __restrict__ imu_beta,
    const float* __restrict__ imu_mean,  const float* __restrict__ imu_var,
    const float* __restrict__ frame_gamma, const float* __restrict__ frame_beta,
    const float* __restrict__ frame_mean,  const float* __restrict__ frame_var,
    const float* __restrict__ b0,
    const float* __restrict__ fc_gamma, const float* __restrict__ fc_beta,
    const float* __restrict__ fc_mean,  const float* __restrict__ fc_var,
    void* __restrict__ ws)
{
    __bf16* w0p    = (__bf16*)ws;
    float* a_fused = (float*)((char*)ws + 262144);
    float* c_fused = a_fused + 512;
    float* A_fc    = c_fused + 512;
    float* C_fc    = A_fc + 256;

    const int b = blockIdx.x;
    if (b < 512) {
        // flat = ((s*16 + t)*64 + lane)*8 + j ; n = t*16+(lane&15); k = s*32+(lane>>4)*8+j
        const int flat = b * 256 + threadIdx.x;
        const int j    = flat & 7;
        const int lane = (flat >> 3) & 63;
        const int t    = (flat >> 9) & 15;
        const int s    = flat >> 13;
        const int n    = t * 16 + (lane & 15);
        const int k    = s * 32 + ((lane >> 4) << 3) + j;
        w0p[flat] = (__bf16)W0[n * 512 + k];
    } else {
        const int t = threadIdx.x;
        const float af = frame_gamma[t] / sqrtf(frame_var[t] + BN_EPS);
        a_fused[t]       = af;
        c_fused[t]       = frame_beta[t] - frame_mean[t] * af;
        const float ai = imu_gamma[t] / sqrtf(imu_var[t] + BN_EPS);
        a_fused[256 + t] = ai;
        c_fused[256 + t] = imu_beta[t] - imu_mean[t] * ai;
        const float A = fc_gamma[t] / sqrtf(fc_var[t] + BN_EPS);
        A_fc[t] = A;
        C_fc[t] = fc_beta[t] - fc_mean[t] * A + A * b0[t];
    }
}

__global__ __launch_bounds__(TPB, 2) void fusion_main(
    const float* __restrict__ frame, const float* __restrict__ imu,
    const float* __restrict__ W1,    const float* __restrict__ b1,
    const void* __restrict__ ws_c,   float* __restrict__ out)
{
    const __bf16* w0p  = (const __bf16*)ws_c;
    const float*  a_g  = (const float*)((const char*)ws_c + 262144);
    const float*  c_g  = a_g + 512;
    const float*  A_fc = c_g + 512;
    const float*  C_fc = A_fc + 256;

    __shared__ __align__(16) __bf16 wpan[2][16384];   // 2 x 32 KB W0 eighth-panels
    __shared__ __align__(16) float  ring[8][4][512];  // per-wave 4-slot feature ring (2 KB slots)
    __shared__ float asx[512], csx[512];              // BN scales (keeps k-loop vmcnt pure-gll)

    const int tid  = threadIdx.x;
    const int wave = tid >> 6;
    const int lane = tid & 63;
    const int nc   = lane & 15;   // A-frag row
    const int kg   = lane >> 4;   // k-group
    const size_t rowBlk = (size_t)blockIdx.x * BM;

    // feature gll lane mapping (instr i): idx = i*64+lane -> row, stored granule; pre-swizzled source
    const int fr0 = lane >> 3;          // i=0: rows 0..7
    const int fg0 = (lane & 7) ^ (fr0 & 7);
    const int fr1 = (64 + lane) >> 3;   // i=1: rows 8..15
    const int fg1 = (lane & 7) ^ (fr1 & 7);

    auto issueF = [&](int s) {
        if (s > 15) return;
        const float* srcp = (s < 8) ? frame : imu;
        char* ldst = (char*)&ring[wave][s & 3][0];
        const int kb = (s & 7) * 32;    // within-modality f32 col base
        gll16(srcp + (rowBlk + wave * 16 + fr0) * 256 + kb + fg0 * 4, ldst);
        gll16(srcp + (rowBlk + wave * 16 + fr1) * 256 + kb + fg1 * 4, ldst + 1024);
    };
    auto issueW = [&](int e) {
        const char* src = (const char*)w0p + e * 32768 + wave * 1024 + lane * 16;
        char* dst = (char*)&wpan[e & 1][0] + wave * 1024;
        #pragma unroll
        for (int i = 0; i < 4; ++i) gll16(src + i * 8192, dst + i * 8192);
    };

    // ---- prologue ----
    asx[tid] = a_g[tid];
    csx[tid] = c_g[tid];
    issueW(0);
    issueF(0);
    issueF(1);
    WAITVM(4);                                   // W0 (and scale loads) retired; F0,F1 in flight
    asm volatile("s_waitcnt lgkmcnt(0)" ::: "memory");   // asx/csx ds_writes visible
    __builtin_amdgcn_s_barrier();

    f32x4 acc[16];
    #pragma unroll
    for (int t = 0; t < 16; ++t) acc[t] = (f32x4){0.f, 0.f, 0.f, 0.f};

    #pragma unroll
    for (int e = 0; e < 8; ++e) {
        if (e < 7) issueW(e + 1);
        #pragma unroll
        for (int s2 = 0; s2 < 2; ++s2) {
            const int s = e * 2 + s2;
            issueF(s + 2);
            if (s <= 13)      { WAITVM(8); }     // retires F(s); queue = F(s+1),W,F(s+2)
            else if (s == 14) { WAITVM(2); }
            else              { WAITVM(0); }
            // pack A-frag: BN+ReLU from ring slot (XOR-swizzled granules)
            const float* sb = &ring[wave][s & 3][0];
            const f32x4 x0 = *(const f32x4*)(sb + nc * 32 + (((2 * kg + 0) ^ (nc & 7)) << 2));
            const f32x4 x1 = *(const f32x4*)(sb + nc * 32 + (((2 * kg + 1) ^ (nc & 7)) << 2));
            const int kf = s * 32 + kg * 8;
            const f32x4 a0 = *(const f32x4*)(asx + kf);
            const f32x4 a1 = *(const f32x4*)(asx + kf + 4);
            const f32x4 c0 = *(const f32x4*)(csx + kf);
            const f32x4 c1 = *(const f32x4*)(csx + kf + 4);
            bf16x8 af;
            af[0] = (__bf16)fmaxf(fmaf(a0[0], x0[0], c0[0]), 0.f);
            af[1] = (__bf16)fmaxf(fmaf(a0[1], x0[1], c0[1]), 0.f);
            af[2] = (__bf16)fmaxf(fmaf(a0[2], x0[2], c0[2]), 0.f);
            af[3] = (__bf16)fmaxf(fmaf(a0[3], x0[3], c0[3]), 0.f);
            af[4] = (__bf16)fmaxf(fmaf(a1[0], x1[0], c1[0]), 0.f);
            af[5] = (__bf16)fmaxf(fmaf(a1[1], x1[1], c1[1]), 0.f);
            af[6] = (__bf16)fmaxf(fmaf(a1[2], x1[2], c1[2]), 0.f);
            af[7] = (__bf16)fmaxf(fmaf(a1[3], x1[3], c1[3]), 0.f);
            // 16 MFMA against the LDS panel (read-only, conflict-free lane-linear)
            const __bf16* pan = &wpan[e & 1][0];
            #pragma unroll
            for (int t = 0; t < 16; ++t) {
                const bf16x8 bfr = *(const bf16x8*)(pan + ((s2 * 16 + t) * 64 + lane) * 8);
                acc[t] = __builtin_amdgcn_mfma_f32_16x16x32_bf16(af, bfr, acc[t], 0, 0, 0);
            }
        }
        if (e < 7) {
            WAITVM(4);                    // own W(e+1) glls retired BEFORE barrier -> dbuf safe
            __builtin_amdgcn_s_barrier(); // all waves done reading wpan[e&1]
        }
    }

    // ---- epilogue: fc BN+ReLU + fc1 + ReLU + clamp ----
    // C/D: col = t*16 + nc, row = kg*4 + q
    float p0[4] = {0.f, 0.f, 0.f, 0.f};
    float p1[4] = {0.f, 0.f, 0.f, 0.f};
    #pragma unroll
    for (int t = 0; t < 16; ++t) {
        const int n = t * 16 + nc;
        const float A = A_fc[n], C = C_fc[n];
        const float w0n = W1[n], w1n = W1[256 + n];
        #pragma unroll
        for (int q = 0; q < 4; ++q) {
            const float h = fmaxf(fmaf(A, acc[t][q], C), 0.f);
            p0[q] = fmaf(h, w0n, p0[q]);
            p1[q] = fmaf(h, w1n, p1[q]);
        }
    }
    #pragma unroll
    for (int off = 1; off < 16; off <<= 1) {
        #pragma unroll
        for (int q = 0; q < 4; ++q) {
            p0[q] += __shfl_xor(p0[q], off, 64);
            p1[q] += __shfl_xor(p1[q], off, 64);
        }
    }
    if (nc < 8) {   // lane nc = q*2+m writes out[row(kg*4+q)][m]
        const int q = nc >> 1, m = nc & 1;
        const float pq0 = (q == 0) ? p0[0] : (q == 1) ? p0[1] : (q == 2) ? p0[2] : p0[3];
        const float pq1 = (q == 0) ? p1[0] : (q == 1) ? p1[1] : (q == 2) ? p1[2] : p1[3];
        float v = (m == 0) ? pq0 : pq1;
        v = fmaxf(v + b1[m], 0.f);
        v = fminf(v, (m == 0) ? 512.f : 384.f);
        const size_t row = rowBlk + wave * 16 + kg * 4 + q;
        out[row * 2 + m] = v;
    }
}

extern "C" void kernel_launch(void* const* d_in, const int* in_sizes, int n_in,
                              void* d_out, int out_size, void* d_ws, size_t ws_size,
                              hipStream_t stream) {
    const float* frame_feat  = (const float*)d_in[0];
    const float* imu_feat    = (const float*)d_in[1];
    const float* imu_gamma   = (const float*)d_in[2];
    const float* imu_beta    = (const float*)d_in[3];
    const float* imu_mean    = (const float*)d_in[4];
    const float* imu_var     = (const float*)d_in[5];
    const float* frame_gamma = (const float*)d_in[6];
    const float* frame_beta  = (const float*)d_in[7];
    const float* frame_mean  = (const float*)d_in[8];
    const float* frame_var   = (const float*)d_in[9];
    const float* W0          = (const float*)d_in[10];
    const float* b0          = (const float*)d_in[11];
    const float* fc_gamma    = (const float*)d_in[12];
    const float* fc_beta     = (const float*)d_in[13];
    const float* fc_mean     = (const float*)d_in[14];
    const float* fc_var      = (const float*)d_in[15];
    const float* W1          = (const float*)d_in[16];
    const float* b1          = (const float*)d_in[17];

    setup_kernel<<<513, 256, 0, stream>>>(
        W0, imu_gamma, imu_beta, imu_mean, imu_var,
        frame_gamma, frame_beta, frame_mean, frame_var,
        b0, fc_gamma, fc_beta, fc_mean, fc_var, d_ws);

    fusion_main<<<NBLOCKS, TPB, 0, stream>>>(
        frame_feat, imu_feat, W1, b1, d_ws, (float*)d_out);
}